// Round 2
// baseline (1470.238 us; speedup 1.0000x reference)
//
#include <hip/hip_runtime.h>

// MeshAttention gfx950 — round 6: barrier-free attention.
// k2_attn: grid 376 = (b,16-row qtile), 512 thr = 8 waves = 8 heads.
//  - Swapped QK^T (S^T = mfma(K,Q)): lane owns column q=l15 -> rowsum/rinv in
//    registers, attn stores are float4 per lane, no LDS P/V staging.
//  - V kept transposed in GLOBAL (vbt[b,h,dv][1504]) -> PV A-operand loads
//    straight to registers.
//  - P^T built in-register: v_cvt_pk_bf16_f32 + ds_bpermute cross-quad swap.
//  - dist staged ONCE per block as u8 [16][1544] (24.7 KB LDS), shared by all
//    heads; ZERO barriers in the K-loops (one after staging).
//  - validf (dist-only) hoisted to its own streaming kernel.
// B=4, H=8, E=1500, D=256, DK=DV=32, P+1=6, mask = dist<=3.

#define E_ 1500
#define D_ 256
#define HH 8
#define BB 4
#define MM (BB * E_)  // 6000
#define NKT_ 24       // K tiles of 64 -> 1536
#define VROW 1504     // vbt row stride (shorts), 3008 B, 16B-aligned

typedef float f32x4 __attribute__((ext_vector_type(4)));
typedef short short8 __attribute__((ext_vector_type(8)));
typedef unsigned uint2v __attribute__((ext_vector_type(2)));

static __device__ inline unsigned short f2bf(float f) {
  unsigned u = __float_as_uint(f);
  unsigned r = (u + 0x7fff + ((u >> 16) & 1)) >> 16;
  return (unsigned short)r;
}
static __device__ inline float bf2f(unsigned short u) {
  return __uint_as_float(((unsigned)u) << 16);
}
static __device__ inline unsigned cvt_pk_bf16(float lo, float hi) {
  unsigned r;
  asm("v_cvt_pk_bf16_f32 %0, %1, %2" : "=v"(r) : "v"(lo), "v"(hi));
  return r;
}

// ------------------------------------------- transpose: x -> xt f32, xtb bf16
__global__ __launch_bounds__(256) void t0_transpose(const float* __restrict__ x,
                                                    float* __restrict__ xt,
                                                    unsigned short* __restrict__ xtb) {
  __shared__ float tl[32][33];
  const int b = blockIdx.z;
  const int dt = blockIdx.x * 32;
  const int et = blockIdx.y * 32;
  const int tx = threadIdx.x, ty = threadIdx.y;
#pragma unroll
  for (int j = 0; j < 4; j++) {
    int d = dt + ty + j * 8;
    int e = et + tx;
    float v = 0.f;
    if (e < E_) v = x[(size_t)b * D_ * E_ + (size_t)d * E_ + e];
    tl[ty + j * 8][tx] = v;
  }
  __syncthreads();
#pragma unroll
  for (int j = 0; j < 4; j++) {
    int e = et + ty + j * 8;
    int d = dt + tx;
    if (e < E_) {
      float v = tl[tx][ty + j * 8];
      size_t idx = ((size_t)b * E_ + e) * D_ + d;
      xt[idx] = v;
      xtb[idx] = f2bf(v);
    }
  }
}

// ------------------------------------------- weight convert+transpose -> bf16
__global__ __launch_bounds__(256) void t1_wt(const float* __restrict__ Wq,
                                             const float* __restrict__ Wk,
                                             const float* __restrict__ Wv,
                                             const float* __restrict__ Wfc,
                                             unsigned short* __restrict__ WT) {
  __shared__ float tl[32][33];
  const int mat = blockIdx.z;
  const float* W = (mat == 0) ? Wq : (mat == 1) ? Wk : (mat == 2) ? Wv : Wfc;
  const int kt = blockIdx.x * 32, nt = blockIdx.y * 32;
  const int tx = threadIdx.x, ty = threadIdx.y;
#pragma unroll
  for (int j = 0; j < 4; j++)
    tl[ty + j * 8][tx] = W[(size_t)(kt + ty + j * 8) * 256 + nt + tx];
  __syncthreads();
#pragma unroll
  for (int j = 0; j < 4; j++)
    WT[(size_t)mat * 65536 + (size_t)(nt + ty + j * 8) * 256 + kt + tx] =
        f2bf(tl[tx][ty + j * 8]);
}

// ---------------------------------------------------------------- layernorm
__global__ __launch_bounds__(256) void k1_ln(const float* __restrict__ xt,
                                             const float* __restrict__ lnw,
                                             const float* __restrict__ lnb,
                                             unsigned short* __restrict__ qnb) {
  const int m = blockIdx.x;
  const int t = threadIdx.x;
  float v = xt[(size_t)m * D_ + t];
  float s = v, s2 = v * v;
#pragma unroll
  for (int o = 1; o < 64; o <<= 1) {
    s += __shfl_xor(s, o);
    s2 += __shfl_xor(s2, o);
  }
  __shared__ float ps[4], ps2[4], mv[2];
  const int w = t >> 6;
  if ((t & 63) == 0) { ps[w] = s; ps2[w] = s2; }
  __syncthreads();
  if (t == 0) {
    float ts = ps[0] + ps[1] + ps[2] + ps[3];
    float ts2 = ps2[0] + ps2[1] + ps2[2] + ps2[3];
    float mu = ts * (1.f / 256.f);
    float var = ts2 * (1.f / 256.f) - mu * mu;
    mv[0] = mu;
    mv[1] = rsqrtf(var + 1e-6f);
  }
  __syncthreads();
  qnb[(size_t)m * D_ + t] = f2bf((v - mv[0]) * mv[1] * lnw[t] + lnb[t]);
}

// ------------------------------------------------- projections, LDS-free mfma
// mat 0=q (scaled, row-major qb), 1=k (row-major kb), 2=v (TRANSPOSED vbt).
__global__ __launch_bounds__(256) void kproj(
    const unsigned short* __restrict__ xtb, const unsigned short* __restrict__ qnb,
    const unsigned short* __restrict__ WT, unsigned short* __restrict__ qb,
    unsigned short* __restrict__ kb, unsigned short* __restrict__ vbt) {
  const int mat = blockIdx.y >> 2;
  const int n0 = (blockIdx.y & 3) * 64;
  const int m0 = blockIdx.x * 64;
  const int t = threadIdx.x;
  const int w = t >> 6, l = t & 63, quad = l >> 4, l15 = l & 15;
  const unsigned short* A = (mat == 0) ? qnb : xtb;
  const unsigned short* B = WT + (size_t)mat * 65536;
  const float scale = (mat == 0) ? 0.17677669529663687f : 1.0f;

  int mrow = m0 + w * 16 + l15;
  if (mrow > MM - 1) mrow = MM - 1;
  short8 af[8];
#pragma unroll
  for (int kc = 0; kc < 8; kc++)
    af[kc] = *(const short8*)(A + (size_t)mrow * 256 + kc * 32 + quad * 8);

#pragma unroll
  for (int ntile = 0; ntile < 4; ntile++) {
    const int n = n0 + ntile * 16 + l15;
    f32x4 acc = {0.f, 0.f, 0.f, 0.f};
#pragma unroll
    for (int kc = 0; kc < 8; kc++) {
      short8 bf = *(const short8*)(B + (size_t)n * 256 + kc * 32 + quad * 8);
      acc = __builtin_amdgcn_mfma_f32_16x16x32_bf16(af[kc], bf, acc, 0, 0, 0);
    }
    if (mat == 2) {
      int m = m0 + w * 16 + quad * 4;
      if (m < MM) {
        int bb = m / E_, e0 = m - bb * E_;
        uint2v uv;
        uv.x = (unsigned)f2bf(acc[0]) | ((unsigned)f2bf(acc[1]) << 16);
        uv.y = (unsigned)f2bf(acc[2]) | ((unsigned)f2bf(acc[3]) << 16);
        *(uint2v*)(vbt + (size_t)((bb * 8 + (n >> 5)) * 32 + (n & 31)) * VROW +
                   e0) = uv;
      }
    } else {
      unsigned short* dst = (mat == 0) ? qb : kb;
#pragma unroll
      for (int r = 0; r < 4; r++) {
        int m = m0 + w * 16 + quad * 4 + r;
        if (m < MM) dst[(size_t)m * 256 + n] = f2bf(acc[r] * scale);
      }
    }
  }
}

// ---------------------------------------------------------------- validf
// validf[b,k] = 8 * sum_q (dist[b,q,k] <= 3)   (dist-only, hoisted out of attn)
__global__ __launch_bounds__(384) void kvalid(const int* __restrict__ dist,
                                              float* __restrict__ validf) {
  const int b = blockIdx.x;
  const int q0 = blockIdx.y * 75;
  const int c = threadIdx.x;
  if (c >= 375) return;
  float a0 = 0, a1 = 0, a2 = 0, a3 = 0;
  const int* base = dist + (size_t)b * E_ * E_ + c * 4;
  for (int q = q0; q < q0 + 75; q++) {
    int4 d = *(const int4*)(base + (size_t)q * E_);
    a0 += (d.x <= 3); a1 += (d.y <= 3); a2 += (d.z <= 3); a3 += (d.w <= 3);
  }
  atomicAdd(validf + b * E_ + c * 4 + 0, a0 * 8.f);
  atomicAdd(validf + b * E_ + c * 4 + 1, a1 * 8.f);
  atomicAdd(validf + b * E_ + c * 4 + 2, a2 * 8.f);
  atomicAdd(validf + b * E_ + c * 4 + 3, a3 * 8.f);
}

// ---------------------------------------------------------------- attention
__global__ __launch_bounds__(512, 4) void k2_attn(
    const unsigned short* __restrict__ qb, const unsigned short* __restrict__ kb,
    const unsigned short* __restrict__ vbt, const int* __restrict__ dist,
    const float* __restrict__ rpr, float* __restrict__ attn,
    unsigned short* __restrict__ aob, float* __restrict__ asum) {
  __shared__ __align__(16) unsigned char dist8[16][1544];  // 24.7 KB, whole K range

  // XCD-bijective swizzle: 376 = 8*47 -> each XCD works one contiguous chunk
  const int id = blockIdx.x;
  const int sw = (id & 7) * 47 + (id >> 3);
  const int b = sw / 94;
  const int qt = sw - b * 94;
  const int q0 = qt * 16;
  const int t = threadIdx.x;
  const int w = t >> 6, l = t & 63, quad = l >> 4, l15 = l & 15;

  // ---- stage dist as u8 [16 q][1544 k] (pad rows/cols with 8 = masked)
  for (int idx = t; idx < 6000; idx += 512) {
    int row = idx / 375, c = idx - row * 375;
    int qg = q0 + row;
    unsigned v = 0x08080808u;
    if (qg < E_) {
      int4 d4 = *(const int4*)(dist + ((size_t)b * E_ + qg) * E_ + c * 4);
      v = (unsigned)(d4.x & 255) | ((unsigned)(d4.y & 255) << 8) |
          ((unsigned)(d4.z & 255) << 16) | ((unsigned)(d4.w & 255) << 24);
    }
    *(unsigned*)&dist8[row][c * 4] = v;
  }
  for (int idx = t; idx < 176; idx += 512) {
    int row = idx / 11, c = idx - row * 11;
    *(unsigned*)&dist8[row][1500 + c * 4] = 0x08080808u;
  }

  // ---- per-wave setup (head w, q column = q0 + l15)
  const int qg = q0 + l15;
  const int qc = (qg < E_) ? qg : (E_ - 1);
  const bool qok = qg < E_;
  const short8 aq =
      *(const short8*)(qb + ((size_t)(b * E_ + qc)) * 256 + w * 32 + quad * 8);

  // qdr[p] = dot(q_scaled, rpr[p]) via partial over own 8 d + quad reduce
  float qd0 = 0, qd1 = 0, qd2 = 0, qd3 = 0;
#pragma unroll
  for (int j = 0; j < 8; j++) {
    float qj = bf2f((unsigned short)aq[j]);
    qd0 += qj * rpr[0 * 32 + quad * 8 + j];
    qd1 += qj * rpr[1 * 32 + quad * 8 + j];
    qd2 += qj * rpr[2 * 32 + quad * 8 + j];
    qd3 += qj * rpr[3 * 32 + quad * 8 + j];
  }
  qd0 += __shfl_xor(qd0, 16); qd0 += __shfl_xor(qd0, 32);
  qd1 += __shfl_xor(qd1, 16); qd1 += __shfl_xor(qd1, 32);
  qd2 += __shfl_xor(qd2, 16); qd2 += __shfl_xor(qd2, 32);
  qd3 += __shfl_xor(qd3, 16); qd3 += __shfl_xor(qd3, 32);

  const unsigned short* kbase = kb + (size_t)b * E_ * 256 + w * 32 + quad * 8;
  size_t vrow0 = (size_t)((b * 8 + w) * 32 + 0 * 16 + l15) * VROW + quad * 8;
  size_t vrow1 = (size_t)((b * 8 + w) * 32 + 1 * 16 + l15) * VROW + quad * 8;

  __syncthreads();  // the ONLY block-wide barrier

  auto loadK = [&](int kt, short8 (&kf)[4]) {
#pragma unroll
    for (int ks = 0; ks < 4; ks++) {
      int kg = kt * 64 + ks * 16 + l15;
      if (kg > E_ - 1) kg = E_ - 1;
      kf[ks] = *(const short8*)(kbase + (size_t)kg * 256);
    }
  };

  f32x4 accOT0 = {0.f, 0.f, 0.f, 0.f}, accOT1 = {0.f, 0.f, 0.f, 0.f};
  float rs = 0.f;
  const int permLo = (((quad & 1) * 2) * 16 + l15) * 4;  // src lane * 4
  const int permHi = permLo + 64;
  const bool hiq = quad >= 2;

  // ================= sweep 1: S^T -> exp -> rs + O^T (no barriers) ==========
  auto body1 = [&](int kt, short8 (&kf)[4], short8 (&kn)[4], bool pf) {
    short8 vf[4];
#pragma unroll
    for (int kc = 0; kc < 2; kc++) {
      vf[kc * 2 + 0] = *(const short8*)(vbt + vrow0 + kt * 64 + kc * 32);
      vf[kc * 2 + 1] = *(const short8*)(vbt + vrow1 + kt * 64 + kc * 32);
    }
    if (pf) loadK(kt + 1, kn);
    const int kl0 = kt * 64;
    f32x4 c[4];
#pragma unroll
    for (int ks = 0; ks < 4; ks++) {
      f32x4 z = {0.f, 0.f, 0.f, 0.f};
      c[ks] = __builtin_amdgcn_mfma_f32_16x16x32_bf16(kf[ks], aq, z, 0, 0, 0);
    }
    float ev[4][4];
#pragma unroll
    for (int ks = 0; ks < 4; ks++) {
      unsigned du = *(const unsigned*)&dist8[l15][kl0 + ks * 16 + quad * 4];
#pragma unroll
      for (int r = 0; r < 4; r++) {
        int dd = (du >> (8 * r)) & 255;
        float qv = (dd & 1) ? ((dd & 2) ? qd3 : qd1) : ((dd & 2) ? qd2 : qd0);
        float e = 0.f;
        if (dd <= 3) e = __expf(c[ks][r] + qv);
        ev[ks][r] = e;
        rs += e;
      }
    }
#pragma unroll
    for (int kc = 0; kc < 2; kc++) {
      // pack own rows (bf16 pairs), then cross-quad bpermute to B-fragment
      unsigned pk0 = cvt_pk_bf16(ev[2 * kc][0], ev[2 * kc][1]);
      unsigned pk1 = cvt_pk_bf16(ev[2 * kc][2], ev[2 * kc][3]);
      unsigned pk2 = cvt_pk_bf16(ev[2 * kc + 1][0], ev[2 * kc + 1][1]);
      unsigned pk3 = cvt_pk_bf16(ev[2 * kc + 1][2], ev[2 * kc + 1][3]);
      unsigned lo0 = __builtin_amdgcn_ds_bpermute(permLo, pk0);
      unsigned hi0 = __builtin_amdgcn_ds_bpermute(permLo, pk2);
      unsigned lo1 = __builtin_amdgcn_ds_bpermute(permLo, pk1);
      unsigned hi1 = __builtin_amdgcn_ds_bpermute(permLo, pk3);
      unsigned lo2 = __builtin_amdgcn_ds_bpermute(permHi, pk0);
      unsigned hi2 = __builtin_amdgcn_ds_bpermute(permHi, pk2);
      unsigned lo3 = __builtin_amdgcn_ds_bpermute(permHi, pk1);
      unsigned hi3 = __builtin_amdgcn_ds_bpermute(permHi, pk3);
      union { unsigned u[4]; short8 s; } uu;
      uu.u[0] = hiq ? hi0 : lo0;
      uu.u[1] = hiq ? hi1 : lo1;
      uu.u[2] = hiq ? hi2 : lo2;
      uu.u[3] = hiq ? hi3 : lo3;
      accOT0 = __builtin_amdgcn_mfma_f32_16x16x32_bf16(vf[kc * 2 + 0], uu.s,
                                                       accOT0, 0, 0, 0);
      accOT1 = __builtin_amdgcn_mfma_f32_16x16x32_bf16(vf[kc * 2 + 1], uu.s,
                                                       accOT1, 0, 0, 0);
    }
  };

  short8 kA[4], kB[4];
  loadK(0, kA);
  for (int kt = 0; kt < NKT_; kt += 2) {
    body1(kt, kA, kB, true);
    body1(kt + 1, kB, kA, kt + 2 < NKT_);
  }

  // rowsum -> rinv (lane-local: column q = l15)
  rs += __shfl_xor(rs, 16);
  rs += __shfl_xor(rs, 32);
  const float rinv = (rs > 0.f) ? 1.f / rs : 0.f;

  // ao = O^T * rinv, bf16, rows dv consecutive -> 8B stores
  if (qok) {
    uint2v u0, u1;
    u0.x = cvt_pk_bf16(accOT0[0] * rinv, accOT0[1] * rinv);
    u0.y = cvt_pk_bf16(accOT0[2] * rinv, accOT0[3] * rinv);
    u1.x = cvt_pk_bf16(accOT1[0] * rinv, accOT1[1] * rinv);
    u1.y = cvt_pk_bf16(accOT1[2] * rinv, accOT1[3] * rinv);
    unsigned short* ap = aob + ((size_t)(b * E_ + qg)) * 256 + w * 32;
    *(uint2v*)(ap + 0 * 16 + quad * 4) = u0;
    *(uint2v*)(ap + 1 * 16 + quad * 4) = u1;
  }

  // ================= sweep 2: recompute -> attn + colsum (no barriers) ======
  const size_t abase = ((size_t)(b * 8 + w) * E_ + qc) * E_;
  auto body2 = [&](int kt, short8 (&kf)[4], short8 (&kn)[4], bool pf) {
    if (pf) loadK(kt + 1, kn);
    const int kl0 = kt * 64;
    f32x4 c[4];
#pragma unroll
    for (int ks = 0; ks < 4; ks++) {
      f32x4 z = {0.f, 0.f, 0.f, 0.f};
      c[ks] = __builtin_amdgcn_mfma_f32_16x16x32_bf16(kf[ks], aq, z, 0, 0, 0);
    }
#pragma unroll
    for (int ks = 0; ks < 4; ks++) {
      unsigned du = *(const unsigned*)&dist8[l15][kl0 + ks * 16 + quad * 4];
      f32x4 p;
#pragma unroll
      for (int r = 0; r < 4; r++) {
        int dd = (du >> (8 * r)) & 255;
        float qv = (dd & 1) ? ((dd & 2) ? qd3 : qd1) : ((dd & 2) ? qd2 : qd0);
        float e = 0.f;
        if (dd <= 3) e = __expf(c[ks][r] + qv) * rinv;
        p[r] = e;
      }
      const int kcol = kl0 + ks * 16 + quad * 4;
      const bool kok = kcol < E_;
      if (qok && kok) *(f32x4*)(attn + abase + kcol) = p;
      // column sums over the 16 q-lanes
#pragma unroll
      for (int o = 1; o < 16; o <<= 1) {
        p[0] += __shfl_xor(p[0], o);
        p[1] += __shfl_xor(p[1], o);
        p[2] += __shfl_xor(p[2], o);
        p[3] += __shfl_xor(p[3], o);
      }
      if (l15 == 0 && kok) {
        atomicAdd(asum + b * E_ + kcol + 0, p[0]);
        atomicAdd(asum + b * E_ + kcol + 1, p[1]);
        atomicAdd(asum + b * E_ + kcol + 2, p[2]);
        atomicAdd(asum + b * E_ + kcol + 3, p[3]);
      }
    }
  };

  loadK(0, kA);
  for (int kt = 0; kt < NKT_; kt += 2) {
    body2(kt, kA, kB, true);
    body2(kt + 1, kB, kA, kt + 2 < NKT_);
  }
}

// ------------------------------------------- FC + residual, LDS-free mfma
__global__ __launch_bounds__(256) void k_fc(const unsigned short* __restrict__ aob,
                                            const unsigned short* __restrict__ WT,
                                            const float* __restrict__ x,
                                            float* __restrict__ xout) {
  const int n0 = blockIdx.y * 64;
  const int m0 = blockIdx.x * 64;
  const int t = threadIdx.x;
  const int w = t >> 6, l = t & 63, quad = l >> 4, l15 = l & 15;
  const unsigned short* B = WT + (size_t)3 * 65536;

  int mrow = m0 + w * 16 + l15;
  if (mrow > MM - 1) mrow = MM - 1;
  short8 af[8];
#pragma unroll
  for (int kc = 0; kc < 8; kc++)
    af[kc] = *(const short8*)(aob + (size_t)mrow * 256 + kc * 32 + quad * 8);

#pragma unroll
  for (int ntile = 0; ntile < 4; ntile++) {
    const int nc = n0 + ntile * 16 + l15;
    f32x4 acc = {0.f, 0.f, 0.f, 0.f};
#pragma unroll
    for (int kc = 0; kc < 8; kc++) {
      short8 bf = *(const short8*)(B + (size_t)nc * 256 + kc * 32 + quad * 8);
      acc = __builtin_amdgcn_mfma_f32_16x16x32_bf16(af[kc], bf, acc, 0, 0, 0);
    }
    int m = m0 + w * 16 + quad * 4;
    if (m < MM) {
      int bb = m / E_, e = m - bb * E_;
      size_t idx = ((size_t)bb * 256 + nc) * E_ + e;
      float4 rx = *(const float4*)(x + idx);
      *(float4*)(xout + idx) = make_float4(acc[0] + rx.x, acc[1] + rx.y,
                                           acc[2] + rx.z, acc[3] + rx.w);
    }
  }
}

__global__ __launch_bounds__(256) void k5_div(const float* __restrict__ asum,
                                              const float* __restrict__ validf,
                                              float* __restrict__ ape) {
  int i = blockIdx.x * 256 + threadIdx.x;
  if (i < BB * E_) ape[i] = asum[i] / validf[i];
}

// ---------------------------------------------------------------- launcher
extern "C" void kernel_launch(void* const* d_in, const int* in_sizes, int n_in,
                              void* d_out, int out_size, void* d_ws,
                              size_t ws_size, hipStream_t stream) {
  const float* x = (const float*)d_in[0];
  const int* dist = (const int*)d_in[1];
  const float* Wq = (const float*)d_in[2];
  const float* Wk = (const float*)d_in[3];
  const float* Wv = (const float*)d_in[4];
  const float* Wfc = (const float*)d_in[5];
  const float* lnw = (const float*)d_in[6];
  const float* lnb = (const float*)d_in[7];
  const float* rpr = (const float*)d_in[8];

  float* out0 = (float*)d_out;
  float* attn = out0 + 1536000;
  float* ape = out0 + 73536000;

  float* ws = (float*)d_ws;
  float* xt = ws;                                            // [6000,256] f32
  unsigned short* xtb = (unsigned short*)(ws + 1536000);     // bf16
  unsigned short* qnb = (unsigned short*)(ws + 2304000);     // bf16
  unsigned short* qb = (unsigned short*)(ws + 3072000);      // bf16
  unsigned short* kb = (unsigned short*)(ws + 3840000);      // bf16
  unsigned short* vbt = (unsigned short*)(ws + 4608000);     // [1024][1504] bf16
  unsigned short* aob = (unsigned short*)(ws + 5378048);     // bf16 [6000,256]
  unsigned short* WT = (unsigned short*)(ws + 6146048);      // [4,256,256] bf16
  float* asum = ws + 6277120;                                // [6000]
  float* validf = ws + 6283120;                              // [6000]

  hipMemsetAsync(asum, 0, 12000 * sizeof(float), stream);
  // zero vbt (incl. pad cols + 16-float margin) so MFMA never sees NaN
  hipMemsetAsync(vbt, 0, (770048 + 16) * sizeof(float), stream);

  t0_transpose<<<dim3(8, 47, 4), dim3(32, 8), 0, stream>>>(x, xt, xtb);
  t1_wt<<<dim3(8, 8, 4), dim3(32, 8), 0, stream>>>(Wq, Wk, Wv, Wfc, WT);
  k1_ln<<<MM, 256, 0, stream>>>(xt, lnw, lnb, qnb);
  kproj<<<dim3(94, 12), 256, 0, stream>>>(xtb, qnb, WT, qb, kb, vbt);
  kvalid<<<dim3(4, 20), 384, 0, stream>>>(dist, validf);
  k2_attn<<<376, 512, 0, stream>>>(qb, kb, vbt, dist, rpr, attn, aob, asum);
  k_fc<<<dim3(94, 4), 256, 0, stream>>>(aob, WT, x, out0);
  k5_div<<<24, 256, 0, stream>>>(asum, validf, ape);
}

// Round 3
// 884.671 us; speedup vs baseline: 1.6619x; 1.6619x over previous
//
#include <hip/hip_runtime.h>

// MeshAttention gfx950 — round 7: barrier-free attention + COALESCED memory.
//  - K/V stored in global in MFMA-fragment order (kbF/vbF): every fragment
//    load is base + lane*16B -> 1KB contiguous per wave instruction.
//  - attn stores go through a per-wave LDS transpose (pT) -> 64B+ runs.
//  - column sums: shfl-reduce -> LDS colacc (ds_add) -> 1 global atomic/col/block.
//  - k_fc epilogue through LDS 64x65 transpose -> coalesced residual reads and
//    xout writes.
// B=4, H=8, E=1500, D=256, DK=DV=32, P+1=6, mask = dist<=3.

#define E_ 1500
#define D_ 256
#define HH 8
#define BB 4
#define MM (BB * E_)  // 6000
#define NKT_ 24       // K tiles of 64 -> 1536

typedef float f32x4 __attribute__((ext_vector_type(4)));
typedef short short8 __attribute__((ext_vector_type(8)));
typedef unsigned uint2v __attribute__((ext_vector_type(2)));

static __device__ inline unsigned short f2bf(float f) {
  unsigned u = __float_as_uint(f);
  unsigned r = (u + 0x7fff + ((u >> 16) & 1)) >> 16;
  return (unsigned short)r;
}
static __device__ inline float bf2f(unsigned short u) {
  return __uint_as_float(((unsigned)u) << 16);
}
static __device__ inline unsigned cvt_pk_bf16(float lo, float hi) {
  unsigned r;
  asm("v_cvt_pk_bf16_f32 %0, %1, %2" : "=v"(r) : "v"(lo), "v"(hi));
  return r;
}

// ------------------------------------------- transpose: x -> xt f32, xtb bf16
__global__ __launch_bounds__(256) void t0_transpose(const float* __restrict__ x,
                                                    float* __restrict__ xt,
                                                    unsigned short* __restrict__ xtb) {
  __shared__ float tl[32][33];
  const int b = blockIdx.z;
  const int dt = blockIdx.x * 32;
  const int et = blockIdx.y * 32;
  const int tx = threadIdx.x, ty = threadIdx.y;
#pragma unroll
  for (int j = 0; j < 4; j++) {
    int d = dt + ty + j * 8;
    int e = et + tx;
    float v = 0.f;
    if (e < E_) v = x[(size_t)b * D_ * E_ + (size_t)d * E_ + e];
    tl[ty + j * 8][tx] = v;
  }
  __syncthreads();
#pragma unroll
  for (int j = 0; j < 4; j++) {
    int e = et + ty + j * 8;
    int d = dt + tx;
    if (e < E_) {
      float v = tl[tx][ty + j * 8];
      size_t idx = ((size_t)b * E_ + e) * D_ + d;
      xt[idx] = v;
      xtb[idx] = f2bf(v);
    }
  }
}

// ------------------------------------------- weight convert+transpose -> bf16
__global__ __launch_bounds__(256) void t1_wt(const float* __restrict__ Wq,
                                             const float* __restrict__ Wk,
                                             const float* __restrict__ Wv,
                                             const float* __restrict__ Wfc,
                                             unsigned short* __restrict__ WT) {
  __shared__ float tl[32][33];
  const int mat = blockIdx.z;
  const float* W = (mat == 0) ? Wq : (mat == 1) ? Wk : (mat == 2) ? Wv : Wfc;
  const int kt = blockIdx.x * 32, nt = blockIdx.y * 32;
  const int tx = threadIdx.x, ty = threadIdx.y;
#pragma unroll
  for (int j = 0; j < 4; j++)
    tl[ty + j * 8][tx] = W[(size_t)(kt + ty + j * 8) * 256 + nt + tx];
  __syncthreads();
#pragma unroll
  for (int j = 0; j < 4; j++)
    WT[(size_t)mat * 65536 + (size_t)(nt + ty + j * 8) * 256 + kt + tx] =
        f2bf(tl[tx][ty + j * 8]);
}

// ---------------------------------------------------------------- layernorm
__global__ __launch_bounds__(256) void k1_ln(const float* __restrict__ xt,
                                             const float* __restrict__ lnw,
                                             const float* __restrict__ lnb,
                                             unsigned short* __restrict__ qnb) {
  const int m = blockIdx.x;
  const int t = threadIdx.x;
  float v = xt[(size_t)m * D_ + t];
  float s = v, s2 = v * v;
#pragma unroll
  for (int o = 1; o < 64; o <<= 1) {
    s += __shfl_xor(s, o);
    s2 += __shfl_xor(s2, o);
  }
  __shared__ float ps[4], ps2[4], mv[2];
  const int w = t >> 6;
  if ((t & 63) == 0) { ps[w] = s; ps2[w] = s2; }
  __syncthreads();
  if (t == 0) {
    float ts = ps[0] + ps[1] + ps[2] + ps[3];
    float ts2 = ps2[0] + ps2[1] + ps2[2] + ps2[3];
    float mu = ts * (1.f / 256.f);
    float var = ts2 * (1.f / 256.f) - mu * mu;
    mv[0] = mu;
    mv[1] = rsqrtf(var + 1e-6f);
  }
  __syncthreads();
  qnb[(size_t)m * D_ + t] = f2bf((v - mv[0]) * mv[1] * lnw[t] + lnb[t]);
}

// ------------------------------------------------- projections, LDS-free mfma
// mat 0=q (scaled, row-major qb), 1=k (FRAGMENT layout kbF), 2=v (FRAGMENT vbF).
// kbF element (b,h,kg,d): idx=((((b*8+h)*24+(kg>>6))*4+((kg>>4)&3))*64+(d>>3)*16+(kg&15))*8+(d&7)
// vbF element (b,h,dv,e): idx=(((((b*8+h)*24+(e>>6))*2+((e>>5)&1))*2+(dv>>4))*64+((e>>3)&3)*16+(dv&15))*8+(e&7)
__global__ __launch_bounds__(256) void kproj(
    const unsigned short* __restrict__ xtb, const unsigned short* __restrict__ qnb,
    const unsigned short* __restrict__ WT, unsigned short* __restrict__ qb,
    unsigned short* __restrict__ kbF, unsigned short* __restrict__ vbF) {
  const int mat = blockIdx.y >> 2;
  const int n0 = (blockIdx.y & 3) * 64;
  const int m0 = blockIdx.x * 64;
  const int t = threadIdx.x;
  const int w = t >> 6, l = t & 63, quad = l >> 4, l15 = l & 15;
  const unsigned short* A = (mat == 0) ? qnb : xtb;
  const unsigned short* B = WT + (size_t)mat * 65536;
  const float scale = (mat == 0) ? 0.17677669529663687f : 1.0f;

  int mrow = m0 + w * 16 + l15;
  if (mrow > MM - 1) mrow = MM - 1;
  short8 af[8];
#pragma unroll
  for (int kc = 0; kc < 8; kc++)
    af[kc] = *(const short8*)(A + (size_t)mrow * 256 + kc * 32 + quad * 8);

#pragma unroll
  for (int ntile = 0; ntile < 4; ntile++) {
    const int n = n0 + ntile * 16 + l15;
    f32x4 acc = {0.f, 0.f, 0.f, 0.f};
#pragma unroll
    for (int kc = 0; kc < 8; kc++) {
      short8 bf = *(const short8*)(B + (size_t)n * 256 + kc * 32 + quad * 8);
      acc = __builtin_amdgcn_mfma_f32_16x16x32_bf16(af[kc], bf, acc, 0, 0, 0);
    }
    if (mat == 1) {
      const int h = n >> 5, d = n & 31;
#pragma unroll
      for (int r = 0; r < 4; r++) {
        int m = m0 + w * 16 + quad * 4 + r;
        if (m < MM) {
          int bb = m / E_;
          int e = m - bb * E_;
          size_t idx =
              ((((size_t)(bb * 8 + h) * 24 + (e >> 6)) * 4 + ((e >> 4) & 3)) * 64 +
               (d >> 3) * 16 + (e & 15)) * 8 + (d & 7);
          kbF[idx] = f2bf(acc[r]);
        }
      }
    } else if (mat == 2) {
      const int h = n >> 5, dv = n & 31;
      int m = m0 + w * 16 + quad * 4;
      if (m < MM) {  // 4-row run stays in one b (1500 % 4 == 0)
        int bb = m / E_;
        int e = m - bb * E_;
        size_t idx =
            (((((size_t)(bb * 8 + h) * 24 + (e >> 6)) * 2 + ((e >> 5) & 1)) * 2 +
              (dv >> 4)) * 64 + ((e >> 3) & 3) * 16 + (dv & 15)) * 8 + (e & 7);
        uint2v uv;
        uv.x = (unsigned)f2bf(acc[0]) | ((unsigned)f2bf(acc[1]) << 16);
        uv.y = (unsigned)f2bf(acc[2]) | ((unsigned)f2bf(acc[3]) << 16);
        *(uint2v*)(vbF + idx) = uv;  // (e&7) in {0,4} -> 8B aligned
      }
    } else {
#pragma unroll
      for (int r = 0; r < 4; r++) {
        int m = m0 + w * 16 + quad * 4 + r;
        if (m < MM) qb[(size_t)m * 256 + n] = f2bf(acc[r] * scale);
      }
    }
  }
}

// ---------------------------------------------------------------- validf
__global__ __launch_bounds__(384) void kvalid(const int* __restrict__ dist,
                                              float* __restrict__ validf) {
  const int b = blockIdx.x;
  const int q0 = blockIdx.y * 75;
  const int c = threadIdx.x;
  if (c >= 375) return;
  float a0 = 0, a1 = 0, a2 = 0, a3 = 0;
  const int* base = dist + (size_t)b * E_ * E_ + c * 4;
  for (int q = q0; q < q0 + 75; q++) {
    int4 d = *(const int4*)(base + (size_t)q * E_);
    a0 += (d.x <= 3); a1 += (d.y <= 3); a2 += (d.z <= 3); a3 += (d.w <= 3);
  }
  atomicAdd(validf + b * E_ + c * 4 + 0, a0 * 8.f);
  atomicAdd(validf + b * E_ + c * 4 + 1, a1 * 8.f);
  atomicAdd(validf + b * E_ + c * 4 + 2, a2 * 8.f);
  atomicAdd(validf + b * E_ + c * 4 + 3, a3 * 8.f);
}

// ---------------------------------------------------------------- attention
// grid 376 = (b, 16-row qtile), 512 thr = 8 waves = 8 heads.
__global__ __launch_bounds__(512, 4) void k2_attn(
    const unsigned short* __restrict__ qb, const unsigned short* __restrict__ kbF,
    const unsigned short* __restrict__ vbF, const int* __restrict__ dist,
    const float* __restrict__ rpr, float* __restrict__ attn,
    unsigned short* __restrict__ aob, float* __restrict__ asum) {
  __shared__ __align__(16) unsigned char dist8[16][1544];  // 24.7 KB
  __shared__ float pT[8][16][68];                          // 34.8 KB, per-wave
  __shared__ float colacc[1544];                           // 6.2 KB

  // XCD-bijective swizzle: 376 = 8*47
  const int id = blockIdx.x;
  const int sw = (id & 7) * 47 + (id >> 3);
  const int b = sw / 94;
  const int qt = sw - b * 94;
  const int q0 = qt * 16;
  const int t = threadIdx.x;
  const int w = t >> 6, l = t & 63, quad = l >> 4, l15 = l & 15;

  // ---- stage dist as u8 [16 q][1544 k] (pad rows/cols with 8 = masked)
  for (int idx = t; idx < 6000; idx += 512) {
    int row = idx / 375, c = idx - row * 375;
    int qg = q0 + row;
    unsigned v = 0x08080808u;
    if (qg < E_) {
      int4 d4 = *(const int4*)(dist + ((size_t)b * E_ + qg) * E_ + c * 4);
      v = (unsigned)(d4.x & 255) | ((unsigned)(d4.y & 255) << 8) |
          ((unsigned)(d4.z & 255) << 16) | ((unsigned)(d4.w & 255) << 24);
    }
    *(unsigned*)&dist8[row][c * 4] = v;
  }
  for (int idx = t; idx < 176; idx += 512) {
    int row = idx / 11, c = idx - row * 11;
    *(unsigned*)&dist8[row][1500 + c * 4] = 0x08080808u;
  }
  for (int idx = t; idx < 1544; idx += 512) colacc[idx] = 0.f;

  // ---- per-wave setup (head w, q column = q0 + l15)
  const int qg = q0 + l15;
  const int qc = (qg < E_) ? qg : (E_ - 1);
  const bool qok = qg < E_;
  const short8 aq =
      *(const short8*)(qb + ((size_t)(b * E_ + qc)) * 256 + w * 32 + quad * 8);

  float qd0 = 0, qd1 = 0, qd2 = 0, qd3 = 0;
#pragma unroll
  for (int j = 0; j < 8; j++) {
    float qj = bf2f((unsigned short)aq[j]);
    qd0 += qj * rpr[0 * 32 + quad * 8 + j];
    qd1 += qj * rpr[1 * 32 + quad * 8 + j];
    qd2 += qj * rpr[2 * 32 + quad * 8 + j];
    qd3 += qj * rpr[3 * 32 + quad * 8 + j];
  }
  qd0 += __shfl_xor(qd0, 16); qd0 += __shfl_xor(qd0, 32);
  qd1 += __shfl_xor(qd1, 16); qd1 += __shfl_xor(qd1, 32);
  qd2 += __shfl_xor(qd2, 16); qd2 += __shfl_xor(qd2, 32);
  qd3 += __shfl_xor(qd3, 16); qd3 += __shfl_xor(qd3, 32);

  const unsigned short* kfb = kbF + (size_t)(b * 8 + w) * 49152;
  const unsigned short* vfb = vbF + (size_t)(b * 8 + w) * 49152;

  __syncthreads();  // the only barrier before the flush

  auto loadK = [&](int kt, short8 (&kf)[4]) {
#pragma unroll
    for (int ks = 0; ks < 4; ks++)
      kf[ks] = *(const short8*)(kfb + (size_t)((kt * 4 + ks) * 64 + l) * 8);
  };

  f32x4 accOT0 = {0.f, 0.f, 0.f, 0.f}, accOT1 = {0.f, 0.f, 0.f, 0.f};
  float rs = 0.f;
  const int permLo = (((quad & 1) * 2) * 16 + l15) * 4;
  const int permHi = permLo + 64;
  const bool hiq = quad >= 2;

  // ================= sweep 1: S^T -> exp -> rs + O^T (no barriers) ==========
  auto body1 = [&](int kt, short8 (&kf)[4], short8 (&kn)[4], bool pf) {
    short8 vf[4];
#pragma unroll
    for (int kc = 0; kc < 2; kc++) {
      vf[kc * 2 + 0] =
          *(const short8*)(vfb + (size_t)(((kt * 2 + kc) * 2 + 0) * 64 + l) * 8);
      vf[kc * 2 + 1] =
          *(const short8*)(vfb + (size_t)(((kt * 2 + kc) * 2 + 1) * 64 + l) * 8);
    }
    if (pf) loadK(kt + 1, kn);
    const int kl0 = kt * 64;
    f32x4 c[4];
#pragma unroll
    for (int ks = 0; ks < 4; ks++) {
      f32x4 z = {0.f, 0.f, 0.f, 0.f};
      c[ks] = __builtin_amdgcn_mfma_f32_16x16x32_bf16(kf[ks], aq, z, 0, 0, 0);
    }
    float ev[4][4];
#pragma unroll
    for (int ks = 0; ks < 4; ks++) {
      unsigned du = *(const unsigned*)&dist8[l15][kl0 + ks * 16 + quad * 4];
#pragma unroll
      for (int r = 0; r < 4; r++) {
        int dd = (du >> (8 * r)) & 255;
        float qv = (dd & 1) ? ((dd & 2) ? qd3 : qd1) : ((dd & 2) ? qd2 : qd0);
        float e = 0.f;
        if (dd <= 3) e = __expf(c[ks][r] + qv);
        ev[ks][r] = e;
        rs += e;
      }
    }
#pragma unroll
    for (int kc = 0; kc < 2; kc++) {
      unsigned pk0 = cvt_pk_bf16(ev[2 * kc][0], ev[2 * kc][1]);
      unsigned pk1 = cvt_pk_bf16(ev[2 * kc][2], ev[2 * kc][3]);
      unsigned pk2 = cvt_pk_bf16(ev[2 * kc + 1][0], ev[2 * kc + 1][1]);
      unsigned pk3 = cvt_pk_bf16(ev[2 * kc + 1][2], ev[2 * kc + 1][3]);
      unsigned lo0 = __builtin_amdgcn_ds_bpermute(permLo, pk0);
      unsigned hi0 = __builtin_amdgcn_ds_bpermute(permLo, pk2);
      unsigned lo1 = __builtin_amdgcn_ds_bpermute(permLo, pk1);
      unsigned hi1 = __builtin_amdgcn_ds_bpermute(permLo, pk3);
      unsigned lo2 = __builtin_amdgcn_ds_bpermute(permHi, pk0);
      unsigned hi2 = __builtin_amdgcn_ds_bpermute(permHi, pk2);
      unsigned lo3 = __builtin_amdgcn_ds_bpermute(permHi, pk1);
      unsigned hi3 = __builtin_amdgcn_ds_bpermute(permHi, pk3);
      union { unsigned u[4]; short8 s; } uu;
      uu.u[0] = hiq ? hi0 : lo0;
      uu.u[1] = hiq ? hi1 : lo1;
      uu.u[2] = hiq ? hi2 : lo2;
      uu.u[3] = hiq ? hi3 : lo3;
      accOT0 = __builtin_amdgcn_mfma_f32_16x16x32_bf16(vf[kc * 2 + 0], uu.s,
                                                       accOT0, 0, 0, 0);
      accOT1 = __builtin_amdgcn_mfma_f32_16x16x32_bf16(vf[kc * 2 + 1], uu.s,
                                                       accOT1, 0, 0, 0);
    }
  };

  short8 kA[4], kB[4];
  loadK(0, kA);
  for (int kt = 0; kt < NKT_; kt += 2) {
    body1(kt, kA, kB, true);
    body1(kt + 1, kB, kA, kt + 2 < NKT_);
  }

  rs += __shfl_xor(rs, 16);
  rs += __shfl_xor(rs, 32);
  const float rinv = (rs > 0.f) ? 1.f / rs : 0.f;

  if (qok) {
    uint2v u0, u1;
    u0.x = cvt_pk_bf16(accOT0[0] * rinv, accOT0[1] * rinv);
    u0.y = cvt_pk_bf16(accOT0[2] * rinv, accOT0[3] * rinv);
    u1.x = cvt_pk_bf16(accOT1[0] * rinv, accOT1[1] * rinv);
    u1.y = cvt_pk_bf16(accOT1[2] * rinv, accOT1[3] * rinv);
    unsigned short* ap = aob + ((size_t)(b * E_ + qg)) * 256 + w * 32;
    *(uint2v*)(ap + 0 * 16 + quad * 4) = u0;
    *(uint2v*)(ap + 1 * 16 + quad * 4) = u1;
  }

  // ================= sweep 2: recompute -> attn (via pT) + colsum ===========
  const int rrow = l >> 2;          // readback row
  const int cbase = (l & 3) * 16;   // readback col base
  const int qg2 = q0 + rrow;
  auto body2 = [&](int kt, short8 (&kf)[4], short8 (&kn)[4], bool pf) {
    if (pf) loadK(kt + 1, kn);
    const int kl0 = kt * 64;
    f32x4 c[4];
#pragma unroll
    for (int ks = 0; ks < 4; ks++) {
      f32x4 z = {0.f, 0.f, 0.f, 0.f};
      c[ks] = __builtin_amdgcn_mfma_f32_16x16x32_bf16(kf[ks], aq, z, 0, 0, 0);
    }
#pragma unroll
    for (int ks = 0; ks < 4; ks++) {
      unsigned du = *(const unsigned*)&dist8[l15][kl0 + ks * 16 + quad * 4];
      f32x4 p;
#pragma unroll
      for (int r = 0; r < 4; r++) {
        int dd = (du >> (8 * r)) & 255;
        float qv = (dd & 1) ? ((dd & 2) ? qd3 : qd1) : ((dd & 2) ? qd2 : qd0);
        float e = 0.f;
        if (dd <= 3) e = __expf(c[ks][r] + qv) * rinv;
        p[r] = e;
      }
      *(f32x4*)&pT[w][l15][ks * 16 + quad * 4] = p;
      float s0 = p[0], s1 = p[1], s2 = p[2], s3 = p[3];
#pragma unroll
      for (int o = 1; o < 16; o <<= 1) {
        s0 += __shfl_xor(s0, o);
        s1 += __shfl_xor(s1, o);
        s2 += __shfl_xor(s2, o);
        s3 += __shfl_xor(s3, o);
      }
      if (l15 == 0) {
        int cb = kl0 + ks * 16 + quad * 4;
        atomicAdd(&colacc[cb + 0], s0);
        atomicAdd(&colacc[cb + 1], s1);
        atomicAdd(&colacc[cb + 2], s2);
        atomicAdd(&colacc[cb + 3], s3);
      }
    }
    // readback (same wave -> LDS ordered) + coalesced stores
    if (qg2 < E_) {
      const size_t rb = ((size_t)(b * 8 + w) * E_ + qg2) * E_ + kl0 + cbase;
#pragma unroll
      for (int i = 0; i < 4; i++) {
        int kc4 = kl0 + cbase + i * 4;
        if (kc4 < E_)
          *(float4*)(attn + rb + i * 4) = *(const float4*)&pT[w][rrow][cbase + i * 4];
      }
    }
  };

  loadK(0, kA);
  for (int kt = 0; kt < NKT_; kt += 2) {
    body2(kt, kA, kB, true);
    body2(kt + 1, kB, kA, kt + 2 < NKT_);
  }

  __syncthreads();
  for (int idx = t; idx < E_; idx += 512)
    atomicAdd(asum + b * E_ + idx, colacc[idx]);
}

// ------------------------------------------- FC + residual, LDS transpose out
__global__ __launch_bounds__(256) void k_fc(const unsigned short* __restrict__ aob,
                                            const unsigned short* __restrict__ WT,
                                            const float* __restrict__ x,
                                            float* __restrict__ xout) {
  __shared__ float tl[64][65];
  const int n0 = blockIdx.y * 64;
  const int m0 = blockIdx.x * 64;
  const int t = threadIdx.x;
  const int w = t >> 6, l = t & 63, quad = l >> 4, l15 = l & 15;
  const unsigned short* B = WT + (size_t)3 * 65536;

  int mrow = m0 + w * 16 + l15;
  if (mrow > MM - 1) mrow = MM - 1;
  short8 af[8];
#pragma unroll
  for (int kc = 0; kc < 8; kc++)
    af[kc] = *(const short8*)(aob + (size_t)mrow * 256 + kc * 32 + quad * 8);

#pragma unroll
  for (int ntile = 0; ntile < 4; ntile++) {
    const int nl = ntile * 16 + l15;
    f32x4 acc = {0.f, 0.f, 0.f, 0.f};
#pragma unroll
    for (int kc = 0; kc < 8; kc++) {
      short8 bf = *(const short8*)(B + (size_t)(n0 + nl) * 256 + kc * 32 + quad * 8);
      acc = __builtin_amdgcn_mfma_f32_16x16x32_bf16(af[kc], bf, acc, 0, 0, 0);
    }
    const int ml = w * 16 + quad * 4;
#pragma unroll
    for (int r = 0; r < 4; r++) tl[ml + r][nl] = acc[r];
  }
  __syncthreads();
  // readback: thread -> out row n0 + (t>>2), e-chunk (t&3)*16
  const int nl = t >> 2;
  const int e0l = (t & 3) * 16;
  const int nc = n0 + nl;
#pragma unroll
  for (int i = 0; i < 4; i++) {
    int m = m0 + e0l + i * 4;
    if (m < MM) {  // float4 never crosses b boundary (1500 % 4 == 0)
      int bb = m / E_;
      int e = m - bb * E_;
      size_t idx = ((size_t)bb * 256 + nc) * E_ + e;
      float4 rx = *(const float4*)(x + idx);
      float4 v = make_float4(tl[e0l + i * 4 + 0][nl] + rx.x,
                             tl[e0l + i * 4 + 1][nl] + rx.y,
                             tl[e0l + i * 4 + 2][nl] + rx.z,
                             tl[e0l + i * 4 + 3][nl] + rx.w);
      *(float4*)(xout + idx) = v;
    }
  }
}

__global__ __launch_bounds__(256) void k5_div(const float* __restrict__ asum,
                                              const float* __restrict__ validf,
                                              float* __restrict__ ape) {
  int i = blockIdx.x * 256 + threadIdx.x;
  if (i < BB * E_) ape[i] = asum[i] / validf[i];
}

// ---------------------------------------------------------------- launcher
extern "C" void kernel_launch(void* const* d_in, const int* in_sizes, int n_in,
                              void* d_out, int out_size, void* d_ws,
                              size_t ws_size, hipStream_t stream) {
  const float* x = (const float*)d_in[0];
  const int* dist = (const int*)d_in[1];
  const float* Wq = (const float*)d_in[2];
  const float* Wk = (const float*)d_in[3];
  const float* Wv = (const float*)d_in[4];
  const float* Wfc = (const float*)d_in[5];
  const float* lnw = (const float*)d_in[6];
  const float* lnb = (const float*)d_in[7];
  const float* rpr = (const float*)d_in[8];

  float* out0 = (float*)d_out;
  float* attn = out0 + 1536000;
  float* ape = out0 + 73536000;

  float* ws = (float*)d_ws;
  float* xt = ws;                                            // [6000,256] f32 (dead after k1_ln)
  unsigned short* kbF = (unsigned short*)ws;                 // aliases xt (written by kproj, after k1_ln)
  unsigned short* xtb = (unsigned short*)(ws + 1536000);     // bf16 [6000,256]
  unsigned short* qnb = (unsigned short*)(ws + 2304000);     // bf16 [6000,256]
  unsigned short* qb = (unsigned short*)(ws + 3072000);      // bf16 [6000,256]
  unsigned short* vbF = (unsigned short*)(ws + 3840000);     // 1,572,864 shorts
  unsigned short* aob = (unsigned short*)(ws + 4626432);     // bf16 [6000,256]
  unsigned short* WT = (unsigned short*)(ws + 5394432);      // [4,256,256] bf16
  float* asum = ws + 5525504;                                // [6000]
  float* validf = ws + 5531504;                              // [6000]

  hipMemsetAsync(asum, 0, 12000 * sizeof(float), stream);
  hipMemsetAsync(vbF, 0, 1572864 * sizeof(unsigned short), stream);  // zero pad rows

  t0_transpose<<<dim3(8, 47, 4), dim3(32, 8), 0, stream>>>(x, xt, xtb);
  t1_wt<<<dim3(8, 8, 4), dim3(32, 8), 0, stream>>>(Wq, Wk, Wv, Wfc, WT);
  k1_ln<<<MM, 256, 0, stream>>>(xt, lnw, lnb, qnb);
  kproj<<<dim3(94, 12), 256, 0, stream>>>(xtb, qnb, WT, qb, kbF, vbF);
  kvalid<<<dim3(4, 20), 384, 0, stream>>>(dist, validf);
  k2_attn<<<376, 512, 0, stream>>>(qb, kbF, vbF, dist, rpr, attn, aob, asum);
  k_fc<<<dim3(94, 4), 256, 0, stream>>>(aob, WT, x, out0);
  k5_div<<<24, 256, 0, stream>>>(asum, validf, ape);
}